// Round 1
// baseline (441.629 us; speedup 1.0000x reference)
//
#include <hip/hip_runtime.h>

// Problem constants
#define BB 4
#define TT 2048
#define CC 1024
#define HH 16
#define DHH 64
// SCALE = 1/sqrt(64) = 0.125

typedef __attribute__((ext_vector_type(8))) __bf16 bf16x8;
typedef __attribute__((ext_vector_type(4))) float f32x4;

__device__ __forceinline__ short f2bf(float f) {
  unsigned u = __float_as_uint(f);
  u += 0x7fffu + ((u >> 16) & 1u);   // round-to-nearest-even
  return (short)(u >> 16);
}

// ---------------- fp32 -> bf16 cast (vectorized float4 -> short4) -------------
__global__ void cvt_bf16(const float* __restrict__ in, short* __restrict__ out, int n4) {
  int i = blockIdx.x * blockDim.x + threadIdx.x;
  if (i >= n4) return;
  float4 f = reinterpret_cast<const float4*>(in)[i];
  short4 s;
  s.x = f2bf(f.x); s.y = f2bf(f.y); s.z = f2bf(f.z); s.w = f2bf(f.w);
  reinterpret_cast<short4*>(out)[i] = s;
}

__device__ __forceinline__ void storev(float* p, float v) { *p = v; }
__device__ __forceinline__ void storev(short* p, float v) { *p = f2bf(v); }

// ---------------- C[M,N] = A[M,K] * B[N,K]^T  (bf16 in, fp32 acc) -------------
// 128x128 tile, 256 threads (4 waves in 2x2), 4x4 16x16x32 MFMA frags per wave.
template <typename OutT>
__global__ __launch_bounds__(256) void gemm_bt(const short* __restrict__ A,
                                               const short* __restrict__ B,
                                               OutT* __restrict__ Cm,
                                               int M, int N, int K) {
  __shared__ __align__(16) short As[128 * 32];
  __shared__ __align__(16) short Bs[128 * 32];
  const int tid = threadIdx.x;
  const int wave = tid >> 6, lane = tid & 63;
  const int quad = lane >> 4, nl = lane & 15;
  const int m0 = blockIdx.x * 128, n0 = blockIdx.y * 128;
  const int wr = (wave >> 1) * 64, wc = (wave & 1) * 64;
  f32x4 acc[4][4] = {};
  for (int k0 = 0; k0 < K; k0 += 32) {
    __syncthreads();
#pragma unroll
    for (int i = 0; i < 2; ++i) {
      int idx = tid + i * 256;
      int row = idx >> 2, cg = idx & 3;
      *reinterpret_cast<uint4*>(&As[row * 32 + cg * 8]) =
          *reinterpret_cast<const uint4*>(&A[(size_t)(m0 + row) * K + k0 + cg * 8]);
      *reinterpret_cast<uint4*>(&Bs[row * 32 + cg * 8]) =
          *reinterpret_cast<const uint4*>(&B[(size_t)(n0 + row) * K + k0 + cg * 8]);
    }
    __syncthreads();
    bf16x8 af[4], bfr[4];
#pragma unroll
    for (int i = 0; i < 4; ++i)
      af[i] = *reinterpret_cast<const bf16x8*>(&As[(wr + i * 16 + nl) * 32 + quad * 8]);
#pragma unroll
    for (int i = 0; i < 4; ++i)
      bfr[i] = *reinterpret_cast<const bf16x8*>(&Bs[(wc + i * 16 + nl) * 32 + quad * 8]);
#pragma unroll
    for (int mi = 0; mi < 4; ++mi)
#pragma unroll
      for (int ni = 0; ni < 4; ++ni)
        acc[mi][ni] = __builtin_amdgcn_mfma_f32_16x16x32_bf16(af[mi], bfr[ni], acc[mi][ni], 0, 0, 0);
  }
#pragma unroll
  for (int mi = 0; mi < 4; ++mi)
#pragma unroll
    for (int ni = 0; ni < 4; ++ni) {
      int row = m0 + wr + mi * 16 + quad * 4;
      int col = n0 + wc + ni * 16 + nl;
#pragma unroll
      for (int r = 0; r < 4; ++r)
        storev(&Cm[(size_t)(row + r) * N + col], acc[mi][ni][r]);
    }
}

// ---------------- causal masked attention (no softmax) ------------------------
// grid: x = T/64 (32 q-blocks of 64 rows), y = B*H (64). block = 256 (4 waves).
// Each wave owns 16 q-rows. S = Q K^T * 0.125 masked; O += S V.
__global__ __launch_bounds__(256) void attn_kernel(const short* __restrict__ qkv,
                                                   short* __restrict__ attnb) {
  const int bh = blockIdx.y;
  const int b = bh >> 4, h = bh & 15;
  const int tid = threadIdx.x;
  const int wave = tid >> 6, lane = tid & 63;
  const int quad = lane >> 4, nl = lane & 15;
  const int qblk = blockIdx.x;
  const int qr0 = qblk * 64 + wave * 16;
  const short* base = qkv + (size_t)b * TT * (3 * CC);

  // Q fragments (A-operand): Q[qr0+m][k], m = nl, k = half*32 + quad*8 + j
  bf16x8 qf[2];
#pragma unroll
  for (int half = 0; half < 2; ++half)
    qf[half] = *reinterpret_cast<const bf16x8*>(
        &base[(size_t)(qr0 + nl) * (3 * CC) + h * DHH + half * 32 + quad * 8]);

  __shared__ __align__(16) short Ks[64 * 64];
  __shared__ __align__(16) short Vs[64 * 64];
  __shared__ __align__(16) short Ss[4][16 * 32];

  f32x4 o[4] = {};
  const int smax = qblk * 64 + 63;  // block-uniform loop bound
  const int tmax = qr0 + 15;        // wave max t

  for (int s0 = 0; s0 <= smax; s0 += 64) {
    __syncthreads();
#pragma unroll
    for (int i = 0; i < 2; ++i) {
      int idx = tid + i * 256;
      int row = idx >> 3, cg = idx & 7;
      *reinterpret_cast<uint4*>(&Ks[row * 64 + cg * 8]) = *reinterpret_cast<const uint4*>(
          &base[(size_t)(s0 + row) * (3 * CC) + CC + h * DHH + cg * 8]);
      *reinterpret_cast<uint4*>(&Vs[row * 64 + cg * 8]) = *reinterpret_cast<const uint4*>(
          &base[(size_t)(s0 + row) * (3 * CC) + 2 * CC + h * DHH + cg * 8]);
    }
    __syncthreads();

#pragma unroll
    for (int sp = 0; sp < 2; ++sp) {
      int sbase = s0 + sp * 32;
      if (sbase > tmax) break;  // wave-uniform
      // two 16x16 S subtiles -> per-wave LDS stage (C-layout -> A-layout)
#pragma unroll
      for (int st = 0; st < 2; ++st) {
        int sb = sbase + st * 16;
        f32x4 sacc = {};
        if (sb <= tmax) {
#pragma unroll
          for (int half = 0; half < 2; ++half) {
            bf16x8 kf = *reinterpret_cast<const bf16x8*>(
                &Ks[(sp * 32 + st * 16 + nl) * 64 + half * 32 + quad * 8]);
            sacc = __builtin_amdgcn_mfma_f32_16x16x32_bf16(qf[half], kf, sacc, 0, 0, 0);
          }
        }
#pragma unroll
        for (int r = 0; r < 4; ++r) {
          int t = qr0 + quad * 4 + r;
          int s = sb + nl;
          float v = (sb <= tmax && s <= t) ? sacc[r] * 0.125f : 0.0f;
          Ss[wave][(quad * 4 + r) * 32 + st * 16 + nl] = f2bf(v);
        }
      }
      // S as A-operand: S[m=nl][k=quad*8+j] over the 32-s pair
      bf16x8 sf = *reinterpret_cast<const bf16x8*>(&Ss[wave][nl * 32 + quad * 8]);
      // V as B-operand: V[k][n] = Vs[sp*32+quad*8+j][nb*16+nl]  (scalar reads)
#pragma unroll
      for (int nb = 0; nb < 4; ++nb) {
        bf16x8 vf;
#pragma unroll
        for (int j = 0; j < 8; ++j) {
          short bits = Vs[(sp * 32 + quad * 8 + j) * 64 + nb * 16 + nl];
          vf[j] = *reinterpret_cast<const __bf16*>(&bits);
        }
        o[nb] = __builtin_amdgcn_mfma_f32_16x16x32_bf16(sf, vf, o[nb], 0, 0, 0);
      }
    }
  }

  // attn in [B,T,C] layout (bf16): attnb[b][t][h*64 + d]
#pragma unroll
  for (int nb = 0; nb < 4; ++nb)
#pragma unroll
    for (int r = 0; r < 4; ++r) {
      int t = qr0 + quad * 4 + r;
      attnb[(size_t)(b * TT + t) * CC + h * DHH + nb * 16 + nl] = f2bf(o[nb][r]);
    }
}

extern "C" void kernel_launch(void* const* d_in, const int* in_sizes, int n_in,
                              void* d_out, int out_size, void* d_ws, size_t ws_size,
                              hipStream_t stream) {
  const float* x = (const float*)d_in[0];      // [4,2048,1024]
  const float* wqkv = (const float*)d_in[1];   // [3072,1024]
  const float* wout = (const float*)d_in[2];   // [1024,1024]
  float* out = (float*)d_out;                  // [4,2048,1024] fp32

  char* ws = (char*)d_ws;
  short* xb    = (short*)(ws);                  // 8192*1024  bf16 = 16.78 MB
  short* wqkvb = (short*)(ws + 16777216);       // 3072*1024  bf16 =  6.29 MB
  short* woutb = (short*)(ws + 23068672);       // 1024*1024  bf16 =  2.10 MB
  short* qkvb  = (short*)(ws + 25165824);       // 8192*3072  bf16 = 50.33 MB
  short* attnb = (short*)(ws + 75497472);       // 8192*1024  bf16 = 16.78 MB
                                                // total 92.27 MB

  // casts
  cvt_bf16<<<(8388608 / 4 + 255) / 256, 256, 0, stream>>>(x, xb, 8388608 / 4);
  cvt_bf16<<<(3145728 / 4 + 255) / 256, 256, 0, stream>>>(wqkv, wqkvb, 3145728 / 4);
  cvt_bf16<<<(1048576 / 4 + 255) / 256, 256, 0, stream>>>(wout, woutb, 1048576 / 4);

  // qkv = x @ W_qkv^T : [8192,3072]
  gemm_bt<short><<<dim3(64, 24), 256, 0, stream>>>(xb, wqkvb, qkvb, 8192, 3072, 1024);

  // attention per (b,h): attnb [B,T,C]
  attn_kernel<<<dim3(32, 64), 256, 0, stream>>>(qkvb, attnb);

  // out = attn @ W_out^T : [8192,1024] fp32
  gemm_bt<float><<<dim3(64, 8), 256, 0, stream>>>(attnb, woutb, out, 8192, 1024, 1024);
}

// Round 2
// 331.646 us; speedup vs baseline: 1.3316x; 1.3316x over previous
//
#include <hip/hip_runtime.h>

#define TT 2048
#define CC 1024

typedef __attribute__((ext_vector_type(8))) __bf16 bf16x8;
typedef __attribute__((ext_vector_type(4))) float f32x4;
typedef unsigned int u32;

__device__ __forceinline__ short f2bf(float f) {
  u32 u = __float_as_uint(f);
  u += 0x7fffu + ((u >> 16) & 1u);  // RTNE
  return (short)(u >> 16);
}
__device__ __forceinline__ u32 pack_rne(float a, float b) {
  u32 ua = __float_as_uint(a), ub = __float_as_uint(b);
  ua += 0x7fffu + ((ua >> 16) & 1u);
  ub += 0x7fffu + ((ub >> 16) & 1u);
  return (ua >> 16) | (ub & 0xffff0000u);  // lo short = a, hi short = b
}

// ---------------- fp32 -> bf16 casts -----------------------------------------
__global__ void cvt_bf16(const float* __restrict__ in, short* __restrict__ out, int n4) {
  int i = blockIdx.x * blockDim.x + threadIdx.x;
  if (i >= n4) return;
  float4 f = reinterpret_cast<const float4*>(in)[i];
  short4 s;
  s.x = f2bf(f.x); s.y = f2bf(f.y); s.z = f2bf(f.z); s.w = f2bf(f.w);
  reinterpret_cast<short4*>(out)[i] = s;
}

// W_qkv cast: scale the Q block (first 1024*1024 elements) by 0.125 so the
// attention kernel needs no per-element scaling (exact: power-of-2).
__global__ void cvt_wqkv(const float* __restrict__ in, short* __restrict__ out, int n4) {
  int i = blockIdx.x * blockDim.x + threadIdx.x;
  if (i >= n4) return;
  float sc = (i * 4 < 1048576) ? 0.125f : 1.0f;
  float4 f = reinterpret_cast<const float4*>(in)[i];
  short4 s;
  s.x = f2bf(f.x * sc); s.y = f2bf(f.y * sc); s.z = f2bf(f.z * sc); s.w = f2bf(f.w * sc);
  reinterpret_cast<short4*>(out)[i] = s;
}

__device__ __forceinline__ void storev(float* p, float v) { *p = v; }
__device__ __forceinline__ void storev(short* p, float v) { *p = f2bf(v); }

#if __has_builtin(__builtin_amdgcn_global_load_lds)
#define HAVE_GLD_LDS 1
__device__ __forceinline__ void gld_lds16(const short* g, short* l) {
  __builtin_amdgcn_global_load_lds((const __attribute__((address_space(1))) u32*)g,
                                   (__attribute__((address_space(3))) u32*)l, 16, 0, 0);
}
#endif

// ---------------- C[M,N] = A[M,K] * B[N,K]^T  (bf16 in, fp32 acc) -------------
// 128x128 tile, 256 threads (4 waves in 2x2), 4x4 16x16x32 MFMA frags per wave.
// Staging via global_load_lds width=16 (LDS layout is lane*16B contiguous).
template <typename OutT>
__global__ __launch_bounds__(256) void gemm_bt(const short* __restrict__ A,
                                               const short* __restrict__ B,
                                               OutT* __restrict__ Cm,
                                               int M, int N, int K) {
  __shared__ __align__(16) short As[128 * 32];
  __shared__ __align__(16) short Bs[128 * 32];
  const int tid = threadIdx.x;
  const int wave = tid >> 6, lane = tid & 63;
  const int quad = lane >> 4, nl = lane & 15;
  const int m0 = blockIdx.x * 128, n0 = blockIdx.y * 128;
  const int wr = (wave >> 1) * 64, wc = (wave & 1) * 64;
  f32x4 acc[4][4] = {};
  for (int k0 = 0; k0 < K; k0 += 32) {
    __syncthreads();
#pragma unroll
    for (int i = 0; i < 2; ++i) {
      int idx = tid + i * 256;
      int row = idx >> 2, cg = idx & 3;
#if HAVE_GLD_LDS
      gld_lds16(&A[(size_t)(m0 + row) * K + k0 + cg * 8], &As[(i * 256 + wave * 64) * 8]);
      gld_lds16(&B[(size_t)(n0 + row) * K + k0 + cg * 8], &Bs[(i * 256 + wave * 64) * 8]);
#else
      *reinterpret_cast<uint4*>(&As[row * 32 + cg * 8]) =
          *reinterpret_cast<const uint4*>(&A[(size_t)(m0 + row) * K + k0 + cg * 8]);
      *reinterpret_cast<uint4*>(&Bs[row * 32 + cg * 8]) =
          *reinterpret_cast<const uint4*>(&B[(size_t)(n0 + row) * K + k0 + cg * 8]);
#endif
    }
    __syncthreads();
    bf16x8 af[4], bfr[4];
#pragma unroll
    for (int i = 0; i < 4; ++i)
      af[i] = *reinterpret_cast<const bf16x8*>(&As[(wr + i * 16 + nl) * 32 + quad * 8]);
#pragma unroll
    for (int i = 0; i < 4; ++i)
      bfr[i] = *reinterpret_cast<const bf16x8*>(&Bs[(wc + i * 16 + nl) * 32 + quad * 8]);
#pragma unroll
    for (int mi = 0; mi < 4; ++mi)
#pragma unroll
      for (int ni = 0; ni < 4; ++ni)
        acc[mi][ni] = __builtin_amdgcn_mfma_f32_16x16x32_bf16(af[mi], bfr[ni], acc[mi][ni], 0, 0, 0);
  }
#pragma unroll
  for (int mi = 0; mi < 4; ++mi)
#pragma unroll
    for (int ni = 0; ni < 4; ++ni) {
      int row = m0 + wr + mi * 16 + quad * 4;
      int col = n0 + wc + ni * 16 + nl;
#pragma unroll
      for (int r = 0; r < 4; ++r)
        storev(&Cm[(size_t)(row + r) * N + col], acc[mi][ni][r]);
    }
}

// ---------------- V transpose: qkv V-part -> Vt[bh][d][t] ---------------------
__global__ __launch_bounds__(256) void transpose_v(const short* __restrict__ qkv,
                                                   short* __restrict__ vt) {
  __shared__ short Ls[64 * 68];  // pad 68: b64 writes (8B-aligned), scalar reads ~8-way max
  const int bh = blockIdx.y, tb = blockIdx.x;
  const int b = bh >> 4, h = bh & 15;
  const int tid = threadIdx.x;
  const short* src = qkv + (size_t)(b * TT + tb * 64) * (3 * CC) + 2 * CC + h * 64;
#pragma unroll
  for (int i = 0; i < 2; ++i) {
    int idx = tid + i * 256;
    int tl = idx >> 3, dc = idx & 7;
    uint4 d4 = *reinterpret_cast<const uint4*>(&src[(size_t)tl * (3 * CC) + dc * 8]);
    *reinterpret_cast<uint2*>(&Ls[tl * 68 + dc * 8]) = make_uint2(d4.x, d4.y);
    *reinterpret_cast<uint2*>(&Ls[tl * 68 + dc * 8 + 4]) = make_uint2(d4.z, d4.w);
  }
  __syncthreads();
  short* dst = vt + (size_t)(bh * 64) * TT + tb * 64;
#pragma unroll
  for (int i = 0; i < 2; ++i) {
    int idx = tid + i * 256;
    int dl = idx >> 3, tc = idx & 7;
    short tmp[8];
#pragma unroll
    for (int j = 0; j < 8; ++j) tmp[j] = Ls[(tc * 8 + j) * 68 + dl];
    *reinterpret_cast<uint4*>(&dst[(size_t)dl * TT + tc * 8]) = *reinterpret_cast<uint4*>(tmp);
  }
}

// ---------------- causal masked attention (no softmax) ------------------------
// grid: (16, 64=B*H), block 256 = 4 waves. Wave w of block kb owns a 32-row
// q-strip, paired (qs, 63-qs) so every block does exactly 66 k-tiles.
// S^T = K·Q^T (MFMA), C-layout -> packed b32 writes into XOR-swizzled per-wave
// LDS -> b128 A-frag reads; PV B-frags read directly from Vt global.
__global__ __launch_bounds__(256) void attn_kernel(const short* __restrict__ qkv,
                                                   const short* __restrict__ vt,
                                                   short* __restrict__ attnb) {
  const int bh = blockIdx.y;
  const int b = bh >> 4, h = bh & 15;
  const int tid = threadIdx.x;
  const int wave = tid >> 6, lane = tid & 63;
  const int quad = lane >> 4, nl = lane & 15;
  const int kb = blockIdx.x;
  const int qs = (wave < 2) ? (2 * kb + wave) : (63 - 2 * kb - (wave - 2));
  const int t0 = qs * 32;

  const short* qbase = qkv + (size_t)(b * TT) * (3 * CC) + h * 64;
  const short* kbase = qbase + CC;
  const short* vbase = vt + (size_t)(bh * 64) * TT;

  __shared__ __align__(16) short Ss[4][2][16 * 64];  // [wave][m][t=16][s=64], chunk-XOR swizzled

  // Q B-fragments (already scaled by 0.125): B[k=d][n=t], lane holds t=nl, d=half*32+quad*8+j
  bf16x8 qf[2][2];
#pragma unroll
  for (int m = 0; m < 2; ++m)
#pragma unroll
    for (int half = 0; half < 2; ++half)
      qf[m][half] = *reinterpret_cast<const bf16x8*>(
          &qbase[(size_t)(t0 + m * 16 + nl) * (3 * CC) + half * 32 + quad * 8]);

  f32x4 o[2][4] = {};
  const int tmax1 = t0 + 31;
  const int sw = nl & 7;

  for (int s0 = 0; s0 <= tmax1; s0 += 64) {
#pragma unroll
    for (int st = 0; st < 4; ++st) {
      const int s16 = s0 + st * 16;
      bf16x8 kA0, kA1;
      if (s16 <= tmax1) {  // A-frag: K[s16+nl][quad*8+j (+32)]
        kA0 = *reinterpret_cast<const bf16x8*>(&kbase[(size_t)(s16 + nl) * (3 * CC) + quad * 8]);
        kA1 = *reinterpret_cast<const bf16x8*>(&kbase[(size_t)(s16 + nl) * (3 * CC) + 32 + quad * 8]);
      }
#pragma unroll
      for (int m = 0; m < 2; ++m) {
        const int tmin = t0 + m * 16, tmaxm = tmin + 15;
        u32* srow = reinterpret_cast<u32*>(&Ss[wave][m][nl * 64]);
        if (s16 > tmaxm) {
          // fully-masked tile: zero-fill only if sibling tile in same 32-chunk is live
          if ((st & 1) && (s16 - 16 <= tmaxm)) {
#pragma unroll
            for (int p = 0; p < 2; ++p) {
              int d32 = st * 8 + quad * 2 + p;
              srow[((d32 >> 2) ^ sw) * 4 + (d32 & 3)] = 0;
            }
          }
          continue;
        }
        f32x4 sacc = {};
        sacc = __builtin_amdgcn_mfma_f32_16x16x32_bf16(kA0, qf[m][0], sacc, 0, 0, 0);
        sacc = __builtin_amdgcn_mfma_f32_16x16x32_bf16(kA1, qf[m][1], sacc, 0, 0, 0);
        if (s16 + 15 > tmin) {  // diagonal tile: per-element causal mask (s <= t)
#pragma unroll
          for (int r = 0; r < 4; ++r)
            sacc[r] = (s16 + quad * 4 + r > tmin + nl) ? 0.0f : sacc[r];
        }
#pragma unroll
        for (int p = 0; p < 2; ++p) {
          int d32 = st * 8 + quad * 2 + p;
          srow[((d32 >> 2) ^ sw) * 4 + (d32 & 3)] = pack_rne(sacc[2 * p], sacc[2 * p + 1]);
        }
      }
    }
    // same-wave produce->consume on Ss: no barrier needed (compiler emits lgkmcnt)
#pragma unroll
    for (int sp = 0; sp < 2; ++sp) {
      const int sc0 = s0 + sp * 32;
      if (sc0 > tmax1) break;  // wave-uniform
      bf16x8 vB[4];  // B[k=s][n=d]: lane holds d=nb*16+nl, s=sc0+quad*8+j (contiguous in Vt)
#pragma unroll
      for (int nb = 0; nb < 4; ++nb)
        vB[nb] = *reinterpret_cast<const bf16x8*>(
            &vbase[(size_t)(nb * 16 + nl) * TT + sc0 + quad * 8]);
#pragma unroll
      for (int m = 0; m < 2; ++m) {
        if (sc0 > t0 + m * 16 + 15) continue;  // whole chunk masked for this m
        bf16x8 sf = *reinterpret_cast<const bf16x8*>(
            &Ss[wave][m][nl * 64 + ((sp * 4 + quad) ^ sw) * 8]);
#pragma unroll
        for (int nb = 0; nb < 4; ++nb)
          o[m][nb] = __builtin_amdgcn_mfma_f32_16x16x32_bf16(sf, vB[nb], o[m][nb], 0, 0, 0);
      }
    }
  }
  // epilogue: O C-layout row=t(quad*4+r), col=d(nl) -> attnb[b][t][h*64+d]
#pragma unroll
  for (int m = 0; m < 2; ++m)
#pragma unroll
    for (int nb = 0; nb < 4; ++nb)
#pragma unroll
      for (int r = 0; r < 4; ++r) {
        int t = t0 + m * 16 + quad * 4 + r;
        attnb[(size_t)(b * TT + t) * CC + h * 64 + nb * 16 + nl] = f2bf(o[m][nb][r]);
      }
}

extern "C" void kernel_launch(void* const* d_in, const int* in_sizes, int n_in,
                              void* d_out, int out_size, void* d_ws, size_t ws_size,
                              hipStream_t stream) {
  const float* x = (const float*)d_in[0];      // [4,2048,1024]
  const float* wqkv = (const float*)d_in[1];   // [3072,1024]
  const float* wout = (const float*)d_in[2];   // [1024,1024]
  float* out = (float*)d_out;                  // [4,2048,1024] fp32

  char* ws = (char*)d_ws;
  short* xb    = (short*)(ws);                  // 16.78 MB
  short* wqkvb = (short*)(ws + 16777216);       //  6.29 MB
  short* woutb = (short*)(ws + 23068672);       //  2.10 MB
  short* qkvb  = (short*)(ws + 25165824);       // 50.33 MB
  short* attnb = (short*)(ws + 75497472);       // 16.78 MB  (total 92.27 MB)
  short* vt    = xb;  // xb is dead after the QKV GEMM; Vt is exactly the same size

  cvt_bf16<<<8192, 256, 0, stream>>>(x, xb, 2097152);
  cvt_wqkv<<<3072, 256, 0, stream>>>(wqkv, wqkvb, 786432);
  cvt_bf16<<<1024, 256, 0, stream>>>(wout, woutb, 262144);

  // qkv = x @ W_qkv^T : [8192,3072] (Q columns pre-scaled by 0.125)
  gemm_bt<short><<<dim3(64, 24), 256, 0, stream>>>(xb, wqkvb, qkvb, 8192, 3072, 1024);

  // Vt[bh][d][t]
  transpose_v<<<dim3(32, 64), 256, 0, stream>>>(qkvb, vt);

  // attention
  attn_kernel<<<dim3(16, 64), 256, 0, stream>>>(qkvb, vt, attnb);

  // out = attn @ W_out^T : [8192,1024] fp32
  gemm_bt<float><<<dim3(64, 8), 256, 0, stream>>>(attnb, woutb, out, 8192, 1024, 1024);
}